// Round 1
// 319.849 us; speedup vs baseline: 1.0669x; 1.0669x over previous
//
#include <hip/hip_runtime.h>
#include <math.h>

#define SEQ  2048
#define CDIM 2048
#define NH   16
#define DH   128
#define HDIM 2048   // NH * DH

typedef __attribute__((ext_vector_type(8))) short  bf16x8;  // 8 bf16 = 4 VGPRs
typedef __attribute__((ext_vector_type(4))) float  f32x4;   // MFMA acc
typedef unsigned short ushort_t;

__device__ __forceinline__ unsigned short f2bf(float f) {   // RNE float->bf16
  unsigned u = __float_as_uint(f);
  u = (u + 0x7fffu + ((u >> 16) & 1u)) >> 16;
  return (unsigned short)u;
}
__device__ __forceinline__ float b2f(unsigned short s) {
  return __uint_as_float((unsigned)s << 16);
}

// async global->LDS, 16B per lane. LDS dest is wave-uniform base + lane*16.
__device__ __forceinline__ void async_ld16(const ushort_t* g, ushort_t* l) {
  __builtin_amdgcn_global_load_lds((const __attribute__((address_space(1))) unsigned int*)g,
                                   (__attribute__((address_space(3))) unsigned int*)l,
                                   16, 0, 0);
}

__device__ __forceinline__ f32x4 mfma16(bf16x8 a, bf16x8 b, f32x4 c) {
  return __builtin_amdgcn_mfma_f32_16x16x32_bf16(a, b, c, 0, 0, 0);
}

// ---------------------------------------------------------------------------
// fp32 -> bf16 pack, 8 elems/thread
// ---------------------------------------------------------------------------
__global__ __launch_bounds__(256) void to_bf16(const float* __restrict__ src,
                                               ushort_t* __restrict__ dst, int n8) {
  int i = blockIdx.x * 256 + threadIdx.x;
  if (i >= n8) return;
  const float4* s = (const float4*)src;
  float4 f0 = s[i * 2], f1 = s[i * 2 + 1];
  bf16x8 o;
  o[0] = (short)f2bf(f0.x); o[1] = (short)f2bf(f0.y);
  o[2] = (short)f2bf(f0.z); o[3] = (short)f2bf(f0.w);
  o[4] = (short)f2bf(f1.x); o[5] = (short)f2bf(f1.y);
  o[6] = (short)f2bf(f1.z); o[7] = (short)f2bf(f1.w);
  *(bf16x8*)&dst[i * 8] = o;
}

// ---------------------------------------------------------------------------
// bf16 MFMA GEMM (NT): C[m][n] = sum_k A[m][k]*B[n][k].  M=N=K=2048.
// 128x128 tile, BK=32, 256 thr (2x2 waves, 64x64/wave, 4x4 MFMA 16x16x32).
// Staging via global_load_lds w=16; XOR chunk swizzle (applied on the global
// source address, LDS stays lane-contiguous) kills the stride-64B conflicts.
// ---------------------------------------------------------------------------
template <int OUT_BF16>
__global__ __launch_bounds__(256) void gemm_bf16(const ushort_t* __restrict__ A,
                                                 const ushort_t* __restrict__ B,
                                                 void* __restrict__ Cv,
                                                 long bStride, long cStride) {
  constexpr int K = CDIM, N = HDIM;
  __shared__ __align__(16) ushort_t As[128 * 32];
  __shared__ __align__(16) ushort_t Bs[128 * 32];
  const ushort_t* Bp = B + (long)blockIdx.z * bStride;
  const int m0 = blockIdx.y * 128, n0 = blockIdx.x * 128;
  const int tid = threadIdx.x, lane = tid & 63, wave = tid >> 6;
  const int wm = wave >> 1, wn = wave & 1;
  const int g = lane >> 4, l15 = lane & 15;
  const int srow = tid >> 2, scc = tid & 3;   // staging: row, 16B-chunk

  f32x4 acc[4][4];
#pragma unroll
  for (int i = 0; i < 4; ++i)
#pragma unroll
    for (int j = 0; j < 4; ++j) acc[i][j] = (f32x4)0.0f;

  for (int k0 = 0; k0 < K; k0 += 32) {
    __syncthreads();
    {
      int r0 = srow, r1 = srow + 64;
      int c0 = scc ^ ((r0 >> 1) & 3), c1 = scc ^ ((r1 >> 1) & 3);
      async_ld16(&A [(long)(m0 + r0) * K + k0 + c0 * 8], &As[wave * 512]);
      async_ld16(&A [(long)(m0 + r1) * K + k0 + c1 * 8], &As[2048 + wave * 512]);
      async_ld16(&Bp[(long)(n0 + r0) * K + k0 + c0 * 8], &Bs[wave * 512]);
      async_ld16(&Bp[(long)(n0 + r1) * K + k0 + c1 * 8], &Bs[2048 + wave * 512]);
    }
    __syncthreads();

    bf16x8 af[4], bfr[4];
#pragma unroll
    for (int mi = 0; mi < 4; ++mi) {
      int row = wm * 64 + mi * 16 + l15;
      int cc = g ^ ((row >> 1) & 3);
      af[mi] = *(const bf16x8*)&As[row * 32 + cc * 8];
    }
#pragma unroll
    for (int ni = 0; ni < 4; ++ni) {
      int row = wn * 64 + ni * 16 + l15;
      int cc = g ^ ((row >> 1) & 3);
      bfr[ni] = *(const bf16x8*)&Bs[row * 32 + cc * 8];
    }
#pragma unroll
    for (int mi = 0; mi < 4; ++mi)
#pragma unroll
      for (int ni = 0; ni < 4; ++ni)
        acc[mi][ni] = mfma16(af[mi], bfr[ni], acc[mi][ni]);
  }

  // epilogue: D layout col=lane&15(n), row=(lane>>4)*4+reg(m)  [m89/m91]
#pragma unroll
  for (int mi = 0; mi < 4; ++mi)
#pragma unroll
    for (int ni = 0; ni < 4; ++ni) {
      int row = m0 + wm * 64 + mi * 16 + g * 4;
      int col = n0 + wn * 64 + ni * 16 + l15;
#pragma unroll
      for (int r = 0; r < 4; ++r) {
        if (OUT_BF16)
          ((ushort_t*)Cv)[cStride * blockIdx.z + (long)(row + r) * N + col] = f2bf(acc[mi][ni][r]);
        else
          ((float*)Cv)[(long)(row + r) * N + col] = acc[mi][ni][r];
      }
    }
}

// ---------------------------------------------------------------------------
// In-place RMSNorm(q,k,v) + RoPE(q,k) + v = l0*v + l1*ve on bf16 qkv.
// One wave per (t,h); thread d holds elems d and d+64 (rotate-half pair).
// ---------------------------------------------------------------------------
__device__ __forceinline__ float wave_sum64(float x) {
#pragma unroll
  for (int m = 32; m >= 1; m >>= 1) x += __shfl_xor(x, m, 64);
  return x;
}

__global__ __launch_bounds__(64) void norm_rope(ushort_t* __restrict__ qkvb,
                                                const float* __restrict__ ve,
                                                const float* __restrict__ lambdas) {
  const int t = blockIdx.x, h = blockIdx.y, d = threadIdx.x;
  const long base = (long)t * HDIM + h * DH;
  ushort_t* q = qkvb + base;
  ushort_t* k = qkvb + (long)SEQ * HDIM + base;
  ushort_t* v = qkvb + 2L * SEQ * HDIM + base;

  float q1 = b2f(q[d]), q2 = b2f(q[d + 64]);
  float k1 = b2f(k[d]), k2 = b2f(k[d + 64]);
  float v1 = b2f(v[d]), v2 = b2f(v[d + 64]);

  float qsc = rsqrtf(wave_sum64(q1 * q1 + q2 * q2) * (1.0f / 128.0f) + 1e-6f);
  float ksc = rsqrtf(wave_sum64(k1 * k1 + k2 * k2) * (1.0f / 128.0f) + 1e-6f);
  float vsc = rsqrtf(wave_sum64(v1 * v1 + v2 * v2) * (1.0f / 128.0f) + 1e-6f);
  q1 *= qsc; q2 *= qsc;
  k1 *= ksc; k2 *= ksc;
  v1 *= vsc; v2 *= vsc;

  float freq = (d < 32) ? powf(1.0f / 1024.0f, (float)d * (1.0f / 31.0f)) : 0.0f;
  float th = (float)t * freq;
  float c = cosf(th), s = sinf(th);

  float qo1 = q1 * c + q2 * s, qo2 = -q1 * s + q2 * c;
  float ko1 = k1 * c + k2 * s, ko2 = -k1 * s + k2 * c;

  float l0 = lambdas[0], l1 = lambdas[1];
  const float* vep = ve + base;
  float vo1 = l0 * v1 + l1 * vep[d];
  float vo2 = l0 * v2 + l1 * vep[d + 64];

  q[d] = f2bf(qo1); q[d + 64] = f2bf(qo2);
  k[d] = f2bf(ko1); k[d + 64] = f2bf(ko2);
  v[d] = f2bf(vo1); v[d + 64] = f2bf(vo2);
}

// ---------------------------------------------------------------------------
// v (bf16, [t][HDIM]) -> vbT ([h][d][t]) so flash can global_load_lds V-tiles.
// ---------------------------------------------------------------------------
__global__ __launch_bounds__(256) void transpose_v(const ushort_t* __restrict__ vb,
                                                   ushort_t* __restrict__ vbT) {
  __shared__ __align__(16) ushort_t L[64 * 136];
  const int t0 = blockIdx.x * 64, h = blockIdx.y;
  const int tid = threadIdx.x;
#pragma unroll
  for (int p = 0; p < 4; ++p) {
    int idx = p * 256 + tid;
    int row = idx >> 4, cc = idx & 15;
    *(bf16x8*)&L[row * 136 + cc * 8] =
        *(const bf16x8*)&vb[(long)(t0 + row) * HDIM + h * DH + cc * 8];
  }
  __syncthreads();
#pragma unroll
  for (int p = 0; p < 4; ++p) {
    int idx = p * 256 + tid;
    int d = idx >> 3, tc = (idx & 7) * 8;
    bf16x8 o;
#pragma unroll
    for (int j = 0; j < 8; ++j) o[j] = (short)L[(tc + j) * 136 + d];
    *(bf16x8*)&vbT[((long)h * DH + d) * SEQ + t0 + tc] = o;
  }
}

// ---------------------------------------------------------------------------
// MFMA flash attention. Block = 64 q-rows x 1 head, 256 thr = 4 waves, each
// wave owns 16 q-rows (2048 waves total -> 2 waves/SIMD vs 1 before).
// S^T = K·Q^T (A=K from LDS, B=Q in regs). P -> wave-private LDS -> A-layout.
// V^T staged from vbT. K/V tiles double-buffered: stage(t+1) issued right
// after the single per-iteration __syncthreads (T3 minimum-2-phase), so the
// HBM latency hides under compute(t). Causal mask only on the diagonal tile.
// ---------------------------------------------------------------------------
__global__ __launch_bounds__(256) void flash_mfma(const ushort_t* __restrict__ qkvb,
                                                  const ushort_t* __restrict__ vbT,
                                                  ushort_t* __restrict__ yb) {
  __shared__ __align__(16) ushort_t Ks[2][64 * 128];
  __shared__ __align__(16) ushort_t Vt[2][128 * 64];
  __shared__ __align__(16) ushort_t Ps[64 * 72];
  const int q0 = blockIdx.x * 64, h = blockIdx.y;
  const int tid = threadIdx.x, lane = tid & 63, wave = tid >> 6;
  const int g = lane >> 4, l15 = lane & 15;
  const ushort_t* Kg = qkvb + (long)SEQ * HDIM;
  const ushort_t* Vg = vbT + (long)h * DH * SEQ;

  // Q fragments (B-operand: B[k=d][n=q], lane n=l15, k=g*8+j), in registers.
  // This wave's 16 q-rows: q = q0 + wave*16 + l15.
  bf16x8 qf[4];
#pragma unroll
  for (int ks = 0; ks < 4; ++ks)
    qf[ks] = *(const bf16x8*)
        &qkvb[(long)(q0 + wave * 16 + l15) * HDIM + h * DH + ks * 32 + g * 8];

  f32x4 oacc[8];
#pragma unroll
  for (int dt = 0; dt < 8; ++dt) oacc[dt] = (f32x4)0.0f;
  float mrow = -1e30f, lrow = 0.0f;

  // stage one 64-key tile (K: 64x128, Vt: 128x64) into buffer buf.
  // 256 thr x 16B x 4 iters per matrix. XOR chunk swizzle on the GLOBAL
  // source address (LDS stays lane-contiguous, as global_load_lds requires).
  auto stage = [&](int buf, int s0) {
#pragma unroll
    for (int i = 0; i < 4; ++i) {
      int idx = i * 256 + tid;
      { int row = idx >> 4, cc = idx & 15, cg = cc ^ (row & 7);   // K: 16 chunks/row
        async_ld16(&Kg[(long)(s0 + row) * HDIM + h * DH + cg * 8],
                   &Ks[buf][i * 2048 + wave * 512]); }
      { int row = idx >> 3, cc = idx & 7,  cg = cc ^ (row & 7);   // Vt: 8 chunks/row
        async_ld16(&Vg[(long)row * SEQ + s0 + cg * 8],
                   &Vt[buf][i * 2048 + wave * 512]); }
    }
  };

  stage(0, 0);
  int cur = 0;
  for (int s0 = 0; s0 <= q0; s0 += 64) {
    __syncthreads();   // drains stage(cur) loads + guards buf reuse (1 barrier/iter)
    if (s0 + 64 <= q0) stage(cur ^ 1, s0 + 64);   // prefetch next tile under compute

    // S^T = K·Q^T : st[mt], C-layout lane: q=l15(col), key=g*4+reg(row)
    f32x4 st[4];
#pragma unroll
    for (int mt = 0; mt < 4; ++mt) st[mt] = (f32x4)0.0f;
#pragma unroll
    for (int ks = 0; ks < 4; ++ks)
#pragma unroll
      for (int mt = 0; mt < 4; ++mt) {
        int row = mt * 16 + l15;
        int cc = (ks * 4 + g) ^ (row & 7);
        bf16x8 a = *(const bf16x8*)&Ks[cur][row * 128 + cc * 8];
        st[mt] = mfma16(a, qf[ks], st[mt]);
      }

    const int qg = q0 + wave * 16 + l15;
    float p[4][4];
#pragma unroll
    for (int mt = 0; mt < 4; ++mt)
#pragma unroll
      for (int r = 0; r < 4; ++r) p[mt][r] = st[mt][r] * 0.12f;
    if (s0 == q0) {                       // only the diagonal tile needs masking
#pragma unroll
      for (int mt = 0; mt < 4; ++mt)
#pragma unroll
        for (int r = 0; r < 4; ++r)
          if (s0 + mt * 16 + g * 4 + r > qg) p[mt][r] = -1e30f;
    }
    float tmax = -1e30f;
#pragma unroll
    for (int mt = 0; mt < 4; ++mt)
#pragma unroll
      for (int r = 0; r < 4; ++r) tmax = fmaxf(tmax, p[mt][r]);
    tmax = fmaxf(tmax, __shfl_xor(tmax, 16, 64));
    tmax = fmaxf(tmax, __shfl_xor(tmax, 32, 64));
    float nm = fmaxf(mrow, tmax);
    float alpha = __expf(mrow - nm);
    float psum = 0.0f;
#pragma unroll
    for (int mt = 0; mt < 4; ++mt) {
      float e0 = __expf(p[mt][0] - nm), e1 = __expf(p[mt][1] - nm);
      float e2 = __expf(p[mt][2] - nm), e3 = __expf(p[mt][3] - nm);
      unsigned short b0 = f2bf(e0), b1 = f2bf(e1), b2 = f2bf(e2), b3 = f2bf(e3);
      psum += b2f(b0) + b2f(b1) + b2f(b2) + b2f(b3);  // l consistent with bf16 P
      unsigned lo = (unsigned)b0 | ((unsigned)b1 << 16);
      unsigned hi = (unsigned)b2 | ((unsigned)b3 << 16);
      *(uint2*)&Ps[(wave * 16 + l15) * 72 + mt * 16 + g * 4] = make_uint2(lo, hi);
    }
    psum += __shfl_xor(psum, 16, 64);
    psum += __shfl_xor(psum, 32, 64);
    mrow = nm;
    lrow = lrow * alpha + psum;

    // rescale O: alpha is keyed by l15; O rows are keyed by g*4+reg -> shfl
    float aO[4];
#pragma unroll
    for (int r = 0; r < 4; ++r) aO[r] = __shfl(alpha, g * 4 + r, 64);
#pragma unroll
    for (int dt = 0; dt < 8; ++dt)
#pragma unroll
      for (int r = 0; r < 4; ++r) oacc[dt][r] *= aO[r];

    // O += P·V  (A=P from wave-private Ps rows, B=V^T from Vt)
#pragma unroll
    for (int ks = 0; ks < 2; ++ks) {
      bf16x8 ap = *(const bf16x8*)&Ps[(wave * 16 + l15) * 72 + ks * 32 + g * 8];
#pragma unroll
      for (int dt = 0; dt < 8; ++dt) {
        int row = dt * 16 + l15;
        int cc = (ks * 4 + g) ^ (row & 7);
        bf16x8 bv = *(const bf16x8*)&Vt[cur][row * 64 + cc * 8];
        oacc[dt] = mfma16(ap, bv, oacc[dt]);
      }
    }
    cur ^= 1;
  }

  float linv[4];
#pragma unroll
  for (int r = 0; r < 4; ++r) linv[r] = 1.0f / __shfl(lrow, g * 4 + r, 64);
#pragma unroll
  for (int dt = 0; dt < 8; ++dt) {
    int row = q0 + wave * 16 + g * 4;
    int col = h * DH + dt * 16 + l15;
#pragma unroll
    for (int r = 0; r < 4; ++r)
      yb[(long)(row + r) * HDIM + col] = f2bf(oacc[dt][r] * linv[r]);
  }
}

// ---------------------------------------------------------------------------
extern "C" void kernel_launch(void* const* d_in, const int* in_sizes, int n_in,
                              void* d_out, int out_size, void* d_ws, size_t ws_size,
                              hipStream_t stream) {
  const float* x       = (const float*)d_in[0];  // (1, 2048, 2048)
  const float* w       = (const float*)d_in[1];  // (4, 2048, 2048)
  const float* ve      = (const float*)d_in[2];  // (1, 2048, 2048)
  const float* lambdas = (const float*)d_in[3];  // (2,)
  float* out = (float*)d_out;

  // ws layout (75.5 MB): qkvb 25.2M | xb 8.4M (reused as yb) | wb 33.6M | vbT 8.4M
  char* ws = (char*)d_ws;
  ushort_t* qkvb = (ushort_t*)ws;                     // [3][SEQ][HDIM] bf16
  ushort_t* xb   = (ushort_t*)(ws + 25165824);        // [SEQ][CDIM]    bf16
  ushort_t* wb   = (ushort_t*)(ws + 33554432);        // [4][HDIM][CDIM] bf16
  ushort_t* vbT  = (ushort_t*)(ws + 67108864);        // [NH][DH][SEQ]  bf16
  ushort_t* yb   = xb;  // xb dead after QKV GEMM

  to_bf16<<<2048, 256, 0, stream>>>(x, xb, (SEQ * CDIM) / 8);
  to_bf16<<<8192, 256, 0, stream>>>(w, wb, (4 * HDIM * CDIM) / 8);
  gemm_bf16<1><<<dim3(16, 16, 3), 256, 0, stream>>>(xb, wb, qkvb,
                                                    (long)HDIM * CDIM, (long)SEQ * HDIM);
  norm_rope<<<dim3(SEQ, NH), 64, 0, stream>>>(qkvb, ve, lambdas);
  transpose_v<<<dim3(SEQ / 64, NH), 256, 0, stream>>>(qkvb + 2L * SEQ * HDIM, vbT);
  flash_mfma<<<dim3(SEQ / 64, NH), 256, 0, stream>>>(qkvb, vbT, yb);
  gemm_bf16<0><<<dim3(16, 16, 1), 256, 0, stream>>>(yb, wb + 3L * HDIM * CDIM, out, 0, 0);
}

// Round 2
// 314.288 us; speedup vs baseline: 1.0858x; 1.0177x over previous
//
#include <hip/hip_runtime.h>
#include <math.h>

#define SEQ  2048
#define CDIM 2048
#define NH   16
#define DH   128
#define HDIM 2048   // NH * DH

typedef __attribute__((ext_vector_type(8))) short  bf16x8;  // 8 bf16 = 4 VGPRs
typedef __attribute__((ext_vector_type(4))) float  f32x4;   // MFMA acc
typedef unsigned short ushort_t;

__device__ __forceinline__ unsigned short f2bf(float f) {   // RNE float->bf16
  unsigned u = __float_as_uint(f);
  u = (u + 0x7fffu + ((u >> 16) & 1u)) >> 16;
  return (unsigned short)u;
}
__device__ __forceinline__ float b2f(unsigned short s) {
  return __uint_as_float((unsigned)s << 16);
}

// async global->LDS, 16B per lane. LDS dest is wave-uniform base + lane*16.
__device__ __forceinline__ void async_ld16(const ushort_t* g, ushort_t* l) {
  __builtin_amdgcn_global_load_lds((const __attribute__((address_space(1))) unsigned int*)g,
                                   (__attribute__((address_space(3))) unsigned int*)l,
                                   16, 0, 0);
}

__device__ __forceinline__ f32x4 mfma16(bf16x8 a, bf16x8 b, f32x4 c) {
  return __builtin_amdgcn_mfma_f32_16x16x32_bf16(a, b, c, 0, 0, 0);
}

// ---------------------------------------------------------------------------
// fp32 -> bf16 pack, 8 elems/thread
// ---------------------------------------------------------------------------
__global__ __launch_bounds__(256) void to_bf16(const float* __restrict__ src,
                                               ushort_t* __restrict__ dst, int n8) {
  int i = blockIdx.x * 256 + threadIdx.x;
  if (i >= n8) return;
  const float4* s = (const float4*)src;
  float4 f0 = s[i * 2], f1 = s[i * 2 + 1];
  bf16x8 o;
  o[0] = (short)f2bf(f0.x); o[1] = (short)f2bf(f0.y);
  o[2] = (short)f2bf(f0.z); o[3] = (short)f2bf(f0.w);
  o[4] = (short)f2bf(f1.x); o[5] = (short)f2bf(f1.y);
  o[6] = (short)f2bf(f1.z); o[7] = (short)f2bf(f1.w);
  *(bf16x8*)&dst[i * 8] = o;
}

// ---------------------------------------------------------------------------
// bf16 MFMA GEMM (NT): C[m][n] = sum_k A[m][k]*B[n][k].  M=N=K=2048.
// 128x128 tile, BK=32, 256 thr (2x2 waves, 64x64/wave, 4x4 MFMA 16x16x32).
// Staging via global_load_lds w=16; XOR chunk swizzle (applied on the global
// source address, LDS stays lane-contiguous) kills the stride-64B conflicts.
// ---------------------------------------------------------------------------
template <int OUT_BF16>
__global__ __launch_bounds__(256) void gemm_bf16(const ushort_t* __restrict__ A,
                                                 const ushort_t* __restrict__ B,
                                                 void* __restrict__ Cv,
                                                 long bStride, long cStride) {
  constexpr int K = CDIM, N = HDIM;
  __shared__ __align__(16) ushort_t As[128 * 32];
  __shared__ __align__(16) ushort_t Bs[128 * 32];
  const ushort_t* Bp = B + (long)blockIdx.z * bStride;
  const int m0 = blockIdx.y * 128, n0 = blockIdx.x * 128;
  const int tid = threadIdx.x, lane = tid & 63, wave = tid >> 6;
  const int wm = wave >> 1, wn = wave & 1;
  const int g = lane >> 4, l15 = lane & 15;
  const int srow = tid >> 2, scc = tid & 3;   // staging: row, 16B-chunk

  f32x4 acc[4][4];
#pragma unroll
  for (int i = 0; i < 4; ++i)
#pragma unroll
    for (int j = 0; j < 4; ++j) acc[i][j] = (f32x4)0.0f;

  for (int k0 = 0; k0 < K; k0 += 32) {
    __syncthreads();
    {
      int r0 = srow, r1 = srow + 64;
      int c0 = scc ^ ((r0 >> 1) & 3), c1 = scc ^ ((r1 >> 1) & 3);
      async_ld16(&A [(long)(m0 + r0) * K + k0 + c0 * 8], &As[wave * 512]);
      async_ld16(&A [(long)(m0 + r1) * K + k0 + c1 * 8], &As[2048 + wave * 512]);
      async_ld16(&Bp[(long)(n0 + r0) * K + k0 + c0 * 8], &Bs[wave * 512]);
      async_ld16(&Bp[(long)(n0 + r1) * K + k0 + c1 * 8], &Bs[2048 + wave * 512]);
    }
    __syncthreads();

    bf16x8 af[4], bfr[4];
#pragma unroll
    for (int mi = 0; mi < 4; ++mi) {
      int row = wm * 64 + mi * 16 + l15;
      int cc = g ^ ((row >> 1) & 3);
      af[mi] = *(const bf16x8*)&As[row * 32 + cc * 8];
    }
#pragma unroll
    for (int ni = 0; ni < 4; ++ni) {
      int row = wn * 64 + ni * 16 + l15;
      int cc = g ^ ((row >> 1) & 3);
      bfr[ni] = *(const bf16x8*)&Bs[row * 32 + cc * 8];
    }
#pragma unroll
    for (int mi = 0; mi < 4; ++mi)
#pragma unroll
      for (int ni = 0; ni < 4; ++ni)
        acc[mi][ni] = mfma16(af[mi], bfr[ni], acc[mi][ni]);
  }

  // epilogue: D layout col=lane&15(n), row=(lane>>4)*4+reg(m)  [m89/m91]
#pragma unroll
  for (int mi = 0; mi < 4; ++mi)
#pragma unroll
    for (int ni = 0; ni < 4; ++ni) {
      int row = m0 + wm * 64 + mi * 16 + g * 4;
      int col = n0 + wn * 64 + ni * 16 + l15;
#pragma unroll
      for (int r = 0; r < 4; ++r) {
        if (OUT_BF16)
          ((ushort_t*)Cv)[cStride * blockIdx.z + (long)(row + r) * N + col] = f2bf(acc[mi][ni][r]);
        else
          ((float*)Cv)[(long)(row + r) * N + col] = acc[mi][ni][r];
      }
    }
}

// ---------------------------------------------------------------------------
// In-place RMSNorm(q,k,v) + RoPE(q,k) + v = l0*v + l1*ve on bf16 qkv.
// One wave per (t,h); thread d holds elems d and d+64 (rotate-half pair).
// ---------------------------------------------------------------------------
__device__ __forceinline__ float wave_sum64(float x) {
#pragma unroll
  for (int m = 32; m >= 1; m >>= 1) x += __shfl_xor(x, m, 64);
  return x;
}

__global__ __launch_bounds__(64) void norm_rope(ushort_t* __restrict__ qkvb,
                                                const float* __restrict__ ve,
                                                const float* __restrict__ lambdas) {
  const int t = blockIdx.x, h = blockIdx.y, d = threadIdx.x;
  const long base = (long)t * HDIM + h * DH;
  ushort_t* q = qkvb + base;
  ushort_t* k = qkvb + (long)SEQ * HDIM + base;
  ushort_t* v = qkvb + 2L * SEQ * HDIM + base;

  float q1 = b2f(q[d]), q2 = b2f(q[d + 64]);
  float k1 = b2f(k[d]), k2 = b2f(k[d + 64]);
  float v1 = b2f(v[d]), v2 = b2f(v[d + 64]);

  float qsc = rsqrtf(wave_sum64(q1 * q1 + q2 * q2) * (1.0f / 128.0f) + 1e-6f);
  float ksc = rsqrtf(wave_sum64(k1 * k1 + k2 * k2) * (1.0f / 128.0f) + 1e-6f);
  float vsc = rsqrtf(wave_sum64(v1 * v1 + v2 * v2) * (1.0f / 128.0f) + 1e-6f);
  q1 *= qsc; q2 *= qsc;
  k1 *= ksc; k2 *= ksc;
  v1 *= vsc; v2 *= vsc;

  float freq = (d < 32) ? powf(1.0f / 1024.0f, (float)d * (1.0f / 31.0f)) : 0.0f;
  float th = (float)t * freq;
  float c = cosf(th), s = sinf(th);

  float qo1 = q1 * c + q2 * s, qo2 = -q1 * s + q2 * c;
  float ko1 = k1 * c + k2 * s, ko2 = -k1 * s + k2 * c;

  float l0 = lambdas[0], l1 = lambdas[1];
  const float* vep = ve + base;
  float vo1 = l0 * v1 + l1 * vep[d];
  float vo2 = l0 * v2 + l1 * vep[d + 64];

  q[d] = f2bf(qo1); q[d + 64] = f2bf(qo2);
  k[d] = f2bf(ko1); k[d + 64] = f2bf(ko2);
  v[d] = f2bf(vo1); v[d + 64] = f2bf(vo2);
}

// ---------------------------------------------------------------------------
// v (bf16, [t][HDIM]) -> vbT ([h][d][t]) so flash can global_load_lds V-tiles.
// ---------------------------------------------------------------------------
__global__ __launch_bounds__(256) void transpose_v(const ushort_t* __restrict__ vb,
                                                   ushort_t* __restrict__ vbT) {
  __shared__ __align__(16) ushort_t L[64 * 136];
  const int t0 = blockIdx.x * 64, h = blockIdx.y;
  const int tid = threadIdx.x;
#pragma unroll
  for (int p = 0; p < 4; ++p) {
    int idx = p * 256 + tid;
    int row = idx >> 4, cc = idx & 15;
    *(bf16x8*)&L[row * 136 + cc * 8] =
        *(const bf16x8*)&vb[(long)(t0 + row) * HDIM + h * DH + cc * 8];
  }
  __syncthreads();
#pragma unroll
  for (int p = 0; p < 4; ++p) {
    int idx = p * 256 + tid;
    int d = idx >> 3, tc = (idx & 7) * 8;
    bf16x8 o;
#pragma unroll
    for (int j = 0; j < 8; ++j) o[j] = (short)L[(tc + j) * 136 + d];
    *(bf16x8*)&vbT[((long)h * DH + d) * SEQ + t0 + tc] = o;
  }
}

// ---------------------------------------------------------------------------
// MFMA flash attention. Block = 64 q-rows x 1 head, 256 thr = 4 waves, each
// wave owns 16 q-rows. K/V tiles double-buffered (stage(t+1) under compute(t)).
// Causal mask only on the diagonal tile.
//
// Work balance: q-block x costs x+1 iterations. Dispatch pairs block b with
// b+256 on the same CU (8 XCDs round-robin, 32 CUs/XCD, 2 blocks/CU), i.e.
// (x,h) with (x,h+8). Remap qi = (h<8) ? x : 31-x so every CU's pair costs
// (x+1)+(32-x) = 33 iterations -> flat critical path (was 2..64).
// ---------------------------------------------------------------------------
__global__ __launch_bounds__(256) void flash_mfma(const ushort_t* __restrict__ qkvb,
                                                  const ushort_t* __restrict__ vbT,
                                                  ushort_t* __restrict__ yb) {
  __shared__ __align__(16) ushort_t Ks[2][64 * 128];
  __shared__ __align__(16) ushort_t Vt[2][128 * 64];
  __shared__ __align__(16) ushort_t Ps[64 * 72];
  const int h = blockIdx.y;
  const int qi = (h < 8) ? blockIdx.x : (31 - blockIdx.x);   // complementary pairing
  const int q0 = qi * 64;
  const int tid = threadIdx.x, lane = tid & 63, wave = tid >> 6;
  const int g = lane >> 4, l15 = lane & 15;
  const ushort_t* Kg = qkvb + (long)SEQ * HDIM;
  const ushort_t* Vg = vbT + (long)h * DH * SEQ;

  // Q fragments (B-operand: B[k=d][n=q], lane n=l15, k=g*8+j), in registers.
  // This wave's 16 q-rows: q = q0 + wave*16 + l15.
  bf16x8 qf[4];
#pragma unroll
  for (int ks = 0; ks < 4; ++ks)
    qf[ks] = *(const bf16x8*)
        &qkvb[(long)(q0 + wave * 16 + l15) * HDIM + h * DH + ks * 32 + g * 8];

  f32x4 oacc[8];
#pragma unroll
  for (int dt = 0; dt < 8; ++dt) oacc[dt] = (f32x4)0.0f;
  float mrow = -1e30f, lrow = 0.0f;

  // stage one 64-key tile (K: 64x128, Vt: 128x64) into buffer buf.
  // 256 thr x 16B x 4 iters per matrix. XOR chunk swizzle on the GLOBAL
  // source address (LDS stays lane-contiguous, as global_load_lds requires).
  auto stage = [&](int buf, int s0) {
#pragma unroll
    for (int i = 0; i < 4; ++i) {
      int idx = i * 256 + tid;
      { int row = idx >> 4, cc = idx & 15, cg = cc ^ (row & 7);   // K: 16 chunks/row
        async_ld16(&Kg[(long)(s0 + row) * HDIM + h * DH + cg * 8],
                   &Ks[buf][i * 2048 + wave * 512]); }
      { int row = idx >> 3, cc = idx & 7,  cg = cc ^ (row & 7);   // Vt: 8 chunks/row
        async_ld16(&Vg[(long)row * SEQ + s0 + cg * 8],
                   &Vt[buf][i * 2048 + wave * 512]); }
    }
  };

  stage(0, 0);
  int cur = 0;
  for (int s0 = 0; s0 <= q0; s0 += 64) {
    __syncthreads();   // drains stage(cur) loads + guards buf reuse (1 barrier/iter)
    if (s0 + 64 <= q0) stage(cur ^ 1, s0 + 64);   // prefetch next tile under compute

    // S^T = K·Q^T : st[mt], C-layout lane: q=l15(col), key=g*4+reg(row)
    f32x4 st[4];
#pragma unroll
    for (int mt = 0; mt < 4; ++mt) st[mt] = (f32x4)0.0f;
    __builtin_amdgcn_s_setprio(1);
#pragma unroll
    for (int ks = 0; ks < 4; ++ks)
#pragma unroll
      for (int mt = 0; mt < 4; ++mt) {
        int row = mt * 16 + l15;
        int cc = (ks * 4 + g) ^ (row & 7);
        bf16x8 a = *(const bf16x8*)&Ks[cur][row * 128 + cc * 8];
        st[mt] = mfma16(a, qf[ks], st[mt]);
      }
    __builtin_amdgcn_s_setprio(0);

    const int qg = q0 + wave * 16 + l15;
    float p[4][4];
#pragma unroll
    for (int mt = 0; mt < 4; ++mt)
#pragma unroll
      for (int r = 0; r < 4; ++r) p[mt][r] = st[mt][r] * 0.12f;
    if (s0 == q0) {                       // only the diagonal tile needs masking
#pragma unroll
      for (int mt = 0; mt < 4; ++mt)
#pragma unroll
        for (int r = 0; r < 4; ++r)
          if (s0 + mt * 16 + g * 4 + r > qg) p[mt][r] = -1e30f;
    }
    float tmax = -1e30f;
#pragma unroll
    for (int mt = 0; mt < 4; ++mt)
#pragma unroll
      for (int r = 0; r < 4; ++r) tmax = fmaxf(tmax, p[mt][r]);
    tmax = fmaxf(tmax, __shfl_xor(tmax, 16, 64));
    tmax = fmaxf(tmax, __shfl_xor(tmax, 32, 64));
    float nm = fmaxf(mrow, tmax);
    float alpha = __expf(mrow - nm);
    float psum = 0.0f;
#pragma unroll
    for (int mt = 0; mt < 4; ++mt) {
      float e0 = __expf(p[mt][0] - nm), e1 = __expf(p[mt][1] - nm);
      float e2 = __expf(p[mt][2] - nm), e3 = __expf(p[mt][3] - nm);
      unsigned short b0 = f2bf(e0), b1 = f2bf(e1), b2 = f2bf(e2), b3 = f2bf(e3);
      psum += b2f(b0) + b2f(b1) + b2f(b2) + b2f(b3);  // l consistent with bf16 P
      unsigned lo = (unsigned)b0 | ((unsigned)b1 << 16);
      unsigned hi = (unsigned)b2 | ((unsigned)b3 << 16);
      *(uint2*)&Ps[(wave * 16 + l15) * 72 + mt * 16 + g * 4] = make_uint2(lo, hi);
    }
    psum += __shfl_xor(psum, 16, 64);
    psum += __shfl_xor(psum, 32, 64);
    mrow = nm;
    lrow = lrow * alpha + psum;

    // rescale O: alpha is keyed by l15; O rows are keyed by g*4+reg -> shfl
    float aO[4];
#pragma unroll
    for (int r = 0; r < 4; ++r) aO[r] = __shfl(alpha, g * 4 + r, 64);
#pragma unroll
    for (int dt = 0; dt < 8; ++dt)
#pragma unroll
      for (int r = 0; r < 4; ++r) oacc[dt][r] *= aO[r];

    // O += P·V  (A=P from wave-private Ps rows, B=V^T from Vt)
    __builtin_amdgcn_s_setprio(1);
#pragma unroll
    for (int ks = 0; ks < 2; ++ks) {
      bf16x8 ap = *(const bf16x8*)&Ps[(wave * 16 + l15) * 72 + ks * 32 + g * 8];
#pragma unroll
      for (int dt = 0; dt < 8; ++dt) {
        int row = dt * 16 + l15;
        int cc = (ks * 4 + g) ^ (row & 7);
        bf16x8 bv = *(const bf16x8*)&Vt[cur][row * 64 + cc * 8];
        oacc[dt] = mfma16(ap, bv, oacc[dt]);
      }
    }
    __builtin_amdgcn_s_setprio(0);
    cur ^= 1;
  }

  float linv[4];
#pragma unroll
  for (int r = 0; r < 4; ++r) linv[r] = 1.0f / __shfl(lrow, g * 4 + r, 64);
#pragma unroll
  for (int dt = 0; dt < 8; ++dt) {
    int row = q0 + wave * 16 + g * 4;
    int col = h * DH + dt * 16 + l15;
#pragma unroll
    for (int r = 0; r < 4; ++r)
      yb[(long)(row + r) * HDIM + col] = f2bf(oacc[dt][r] * linv[r]);
  }
}

// ---------------------------------------------------------------------------
extern "C" void kernel_launch(void* const* d_in, const int* in_sizes, int n_in,
                              void* d_out, int out_size, void* d_ws, size_t ws_size,
                              hipStream_t stream) {
  const float* x       = (const float*)d_in[0];  // (1, 2048, 2048)
  const float* w       = (const float*)d_in[1];  // (4, 2048, 2048)
  const float* ve      = (const float*)d_in[2];  // (1, 2048, 2048)
  const float* lambdas = (const float*)d_in[3];  // (2,)
  float* out = (float*)d_out;

  // ws layout (75.5 MB): qkvb 25.2M | xb 8.4M (reused as yb) | wb 33.6M | vbT 8.4M
  char* ws = (char*)d_ws;
  ushort_t* qkvb = (ushort_t*)ws;                     // [3][SEQ][HDIM] bf16
  ushort_t* xb   = (ushort_t*)(ws + 25165824);        // [SEQ][CDIM]    bf16
  ushort_t* wb   = (ushort_t*)(ws + 33554432);        // [4][HDIM][CDIM] bf16
  ushort_t* vbT  = (ushort_t*)(ws + 67108864);        // [NH][DH][SEQ]  bf16
  ushort_t* yb   = xb;  // xb dead after QKV GEMM

  to_bf16<<<2048, 256, 0, stream>>>(x, xb, (SEQ * CDIM) / 8);
  to_bf16<<<8192, 256, 0, stream>>>(w, wb, (4 * HDIM * CDIM) / 8);
  gemm_bf16<1><<<dim3(16, 16, 3), 256, 0, stream>>>(xb, wb, qkvb,
                                                    (long)HDIM * CDIM, (long)SEQ * HDIM);
  norm_rope<<<dim3(SEQ, NH), 64, 0, stream>>>(qkvb, ve, lambdas);
  transpose_v<<<dim3(SEQ / 64, NH), 256, 0, stream>>>(qkvb + 2L * SEQ * HDIM, vbT);
  flash_mfma<<<dim3(SEQ / 64, NH), 256, 0, stream>>>(qkvb, vbT, yb);
  gemm_bf16<0><<<dim3(16, 16, 1), 256, 0, stream>>>(yb, wb + 3L * HDIM * CDIM, out, 0, 0);
}